// Round 4
// baseline (2611.927 us; speedup 1.0000x reference)
//
#include <hip/hip_runtime.h>
#include <hip/hip_bf16.h>
#include <math.h>

typedef unsigned short u16;
typedef __attribute__((ext_vector_type(8))) short s16x8;
typedef __attribute__((ext_vector_type(4))) float f32x4;

#define B_ 4
#define N_ 4096
#define C_ 1024
#define M_ (B_*N_)

__device__ __forceinline__ u16 f2bf(float f) {
  unsigned u = __builtin_bit_cast(unsigned, f);
  u = u + 0x7fffu + ((u >> 16) & 1u);
  return (u16)(u >> 16);
}
__device__ __forceinline__ float bf2f(u16 h) {
  unsigned u = ((unsigned)h) << 16;
  return __builtin_bit_cast(float, u);
}

// ---------------- kernel T: one-time rope trig table (512 pairs) ----------------
__global__ void trig_kernel(float* __restrict__ ctab, float* __restrict__ stab) {
  const int i = threadIdx.x;   // 0..511
  const float theta = powf(10000.f, -(float)i * (1.f/512.f));
  ctab[i] = cosf(theta);
  stab[i] = sinf(theta);
}

// ---------------- kernel 0: fp32 -> bf16 precast of x and W ----------------
__global__ __launch_bounds__(256) void cast_kernel(
    const float* __restrict__ x, const float* __restrict__ w,
    u16* __restrict__ xb, u16* __restrict__ wb)
{
  const int NX4 = M_*C_/4;     // 4194304
  const int NW4 = 2048*C_/4;   // 524288
  int tid = blockIdx.x*256 + threadIdx.x;
  int stride = gridDim.x*256;
  for (int i = tid; i < NX4; i += stride) {
    f32x4 v = ((const f32x4*)x)[i];
    ushort4 o;
    o.x = f2bf(v[0]); o.y = f2bf(v[1]); o.z = f2bf(v[2]); o.w = f2bf(v[3]);
    ((ushort4*)xb)[i] = o;
  }
  for (int i = tid; i < NW4; i += stride) {
    f32x4 v = ((const f32x4*)w)[i];
    ushort4 o;
    o.x = f2bf(v[0]); o.y = f2bf(v[1]); o.z = f2bf(v[2]); o.w = f2bf(v[3]);
    ((ushort4*)wb)[i] = o;
  }
}

// ---------------- kernel 1: qk GEMM + bias + elu+1 -> q,k (bf16) ----------------
// C[m, n] = sum_k xb[m,k] * wb[n,k]   (B^T layout), m=16384, n=2048, k=1024
// 128x128 tile, BK=64, 4 waves (2x2), mfma_f32_16x16x32_bf16
__global__ __launch_bounds__(256) void gemm_kernel(
    const u16* __restrict__ xb, const u16* __restrict__ wb,
    const float* __restrict__ bqk,
    u16* __restrict__ qb, u16* __restrict__ kb)
{
  __shared__ __align__(16) unsigned char As[16384];  // 128 rows x 128B (64 bf16)
  __shared__ __align__(16) unsigned char Bs[16384];
  const int t = threadIdx.x;
  const int l = t & 63;
  const int w = t >> 6;
  const int wm = w >> 1, wn = w & 1;
  const int m0 = blockIdx.x * 128;
  const int n0 = blockIdx.y * 128;

  f32x4 acc[4][4];
  #pragma unroll
  for (int a = 0; a < 4; ++a)
    #pragma unroll
    for (int b = 0; b < 4; ++b) acc[a][b] = (f32x4){0.f,0.f,0.f,0.f};

  for (int kt = 0; kt < 1024; kt += 64) {
    __syncthreads();
    // stage A,B: linear LDS dest; inverse-swizzled global source (rule #21)
    #pragma unroll
    for (int i = 0; i < 4; ++i) {
      const int jc   = i*256 + t;                       // 16B chunk id 0..1023
      const int row  = jc >> 3;                         // 0..127
      const int colb = ((jc & 7) << 4) ^ ((row & 7) << 4); // source col byte
      const int cole = colb >> 1;                       // bf16 elem col
      const int ldsoff = (i*256 + w*64) * 16;           // wave-uniform base
      __builtin_amdgcn_global_load_lds(
        (const __attribute__((address_space(1))) void*)(xb + (size_t)(m0 + row)*1024 + kt + cole),
        (__attribute__((address_space(3))) void*)(As + ldsoff), 16, 0, 0);
      __builtin_amdgcn_global_load_lds(
        (const __attribute__((address_space(1))) void*)(wb + (size_t)(n0 + row)*1024 + kt + cole),
        (__attribute__((address_space(3))) void*)(Bs + ldsoff), 16, 0, 0);
    }
    __syncthreads();

    #pragma unroll
    for (int ks = 0; ks < 2; ++ks) {
      const int kbyte = ks*64 + ((l >> 4) << 4);
      s16x8 af[4], bff[4];
      #pragma unroll
      for (int mi = 0; mi < 4; ++mi) {
        const int r = wm*64 + mi*16 + (l & 15);
        af[mi] = *(const s16x8*)(As + r*128 + (kbyte ^ ((r & 7) << 4)));
      }
      #pragma unroll
      for (int ni = 0; ni < 4; ++ni) {
        const int r = wn*64 + ni*16 + (l & 15);
        bff[ni] = *(const s16x8*)(Bs + r*128 + (kbyte ^ ((r & 7) << 4)));
      }
      #pragma unroll
      for (int mi = 0; mi < 4; ++mi)
        #pragma unroll
        for (int ni = 0; ni < 4; ++ni)
          acc[mi][ni] = __builtin_amdgcn_mfma_f32_16x16x32_bf16(af[mi], bff[ni], acc[mi][ni], 0, 0, 0);
    }
  }

  // epilogue: bias + elu + 1, split to q / k buffers (block is uniformly q or k)
  #pragma unroll
  for (int ni = 0; ni < 4; ++ni) {
    const int col = n0 + wn*64 + ni*16 + (l & 15);   // 0..2047
    const float bias = bqk[col];
    u16* dst = (col < 1024) ? qb : kb;
    const int cc = col & 1023;
    #pragma unroll
    for (int mi = 0; mi < 4; ++mi) {
      #pragma unroll
      for (int j = 0; j < 4; ++j) {
        const int rowm = m0 + wm*64 + mi*16 + ((l >> 4) << 2) + j;
        float v = acc[mi][ni][j] + bias;
        v = (v > 0.f) ? (v + 1.f) : __expf(v);      // elu(v)+1
        dst[(size_t)rowm*1024 + cc] = f2bf(v);
      }
    }
  }
}

// ---------------- kernel 2: kv[b,h,d,e] and kmean[b,h,d] ----------------
// kv = (1/n) sum_n k_rope[n,d] * v[n,e];  kmean = mean_n k[n,d]
// grid 512 = (b,h) x 8 n-slices; thread t: d = t>>2, e-range = (t&3)*16..+16
__global__ __launch_bounds__(256, 4) void kv_kernel(
    const u16* __restrict__ kb, const u16* __restrict__ xb,
    const float* __restrict__ ctab, const float* __restrict__ stab,
    float* __restrict__ kv, float* __restrict__ kmean)
{
  const int blk = blockIdx.x;
  const int ns = blk & 7;
  const int bh = blk >> 3;             // 0..63
  const int b = bh >> 4, h = bh & 15;
  const int t = threadIdx.x;
  const int d = t >> 2;
  const int eg = t & 3;
  const int e0 = eg * 16;

  const int p = (h*64 + d) >> 1;       // rope pair index (constant per thread)
  const float cn = ctab[p];
  const float sn0 = stab[p];
  const float sgn = (d & 1) ? sn0 : -sn0;   // kr = cn*k[d] + sgn*k[d^1]

  float kvacc[16];
  #pragma unroll
  for (int i = 0; i < 16; ++i) kvacc[i] = 0.f;
  float ksum = 0.f;

  const size_t base = ((size_t)b*4096 + ns*512) * 1024 + h*64;
  for (int n = 0; n < 512; ++n) {
    const size_t roff = base + (size_t)n * 1024;
    const float kd = bf2f(kb[roff + d]);
    const float kp = bf2f(kb[roff + (d ^ 1)]);
    const float kr = cn*kd + sgn*kp;
    ksum += kd;
    const s16x8 v0 = *(const s16x8*)(xb + roff + e0);
    const s16x8 v1 = *(const s16x8*)(xb + roff + e0 + 8);
    #pragma unroll
    for (int i = 0; i < 8; ++i) kvacc[i]     += kr * bf2f((u16)v0[i]);
    #pragma unroll
    for (int i = 0; i < 8; ++i) kvacc[8 + i] += kr * bf2f((u16)v1[i]);
  }
  const float inv_n = 1.f / 4096.f;
  float* dst = kv + ((size_t)bh*64 + d)*64 + e0;
  #pragma unroll
  for (int i = 0; i < 16; ++i) atomicAdd(dst + i, kvacc[i] * inv_n);
  if (eg == 0) atomicAdd(kmean + bh*64 + d, ksum * inv_n);
}

// ---------------- kernel 3: z, attn = q_rope @ kv * z, + depthwise-conv pe ----------------
// grid (64 ntiles, 16 h, 4 b) = 4096 blocks; block = 256 threads = 64 rows x 4 e-groups.
// __launch_bounds__(256,4): cap VGPR at 128 so the scheduler can't hoist past the
// 256-reg cap and spill (R1-R3 signature: VGPR=256, 2.6GB scratch writes).
__global__ __launch_bounds__(256, 4) void out_kernel(
    const u16* __restrict__ qb, const float* __restrict__ kv,
    const float* __restrict__ kmean, const float* __restrict__ x,
    const float* __restrict__ lw, const float* __restrict__ lb,
    const float* __restrict__ ctab, const float* __restrict__ stab,
    float* __restrict__ out)
{
  __shared__ __align__(16) float kvs[4096];   // kv[d][e] for this (b,h): 16 KB
  __shared__ float kms[64];
  __shared__ float csc[32], css[32];
  __shared__ float lws[64*3], lbs[64];

  const int t  = threadIdx.x;
  const int nt = blockIdx.x;
  const int h  = blockIdx.y;
  const int b  = blockIdx.z;

  // stage kv tile (16 KB), kmean slice, rope table, lepe weights
  const float* kvsrc = kv + (size_t)(b*16 + h) * 4096;
  #pragma unroll
  for (int i = 0; i < 4; ++i)
    ((f32x4*)kvs)[i*256 + t] = ((const f32x4*)kvsrc)[i*256 + t];
  if (t < 64)  kms[t] = kmean[(b*16 + h)*64 + t];
  if (t < 32) { csc[t] = ctab[h*32 + t]; css[t] = stab[h*32 + t]; }
  if (t >= 64 && t < 256) {
    const int i = t - 64;                 // 0..191
    lws[i] = lw[h*192 + i];               // lw[(h*64+ch)*3 + j]
  }
  if (t >= 32 && t < 96) lbs[t-32] = lb[h*64 + (t-32)];
  __syncthreads();

  const int r  = t >> 2;                  // row 0..63
  const int eg = t & 3;                   // e/d quarter
  const int n  = nt*64 + r;               // 0..4095 within batch b
  const size_t rowx = ((size_t)b*4096 + n) * 1024;

  // q chunk: 16 bf16
  const u16* qrow = qb + rowx + h*64 + eg*16;
  const s16x8 q0 = *(const s16x8*)qrow;
  const s16x8 q1 = *(const s16x8*)(qrow + 8);
  float qf[16];
  #pragma unroll
  for (int i = 0; i < 8; ++i) { qf[i] = bf2f((u16)q0[i]); qf[8+i] = bf2f((u16)q1[i]); }

  // z = 1/(q . kmean + 1e-6): 4-lane-group reduce
  float zp = 0.f;
  #pragma unroll
  for (int i = 0; i < 16; ++i) zp += qf[i] * kms[eg*16 + i];
  zp += __shfl_xor(zp, 1);
  zp += __shfl_xor(zp, 2);
  const float z = 1.f / (zp + 1e-6f);

  // rope q in registers (pairs are inside the 16-chunk; eg*16 is even)
  float qr[16];
  #pragma unroll
  for (int i = 0; i < 16; i += 2) {
    const int p = eg*8 + (i >> 1);        // local pair index within head
    const float cn = csc[p], sn = css[p];
    qr[i]   = cn*qf[i]   - sn*qf[i+1];
    qr[i+1] = sn*qf[i]   + cn*qf[i+1];
  }

  // attn[e0..e0+15] = sum_d qr_full[d] * kv[d][e]; full d via shfl_xor over 4-lane group
  f32x4 acc4[4];
  #pragma unroll
  for (int c = 0; c < 4; ++c) acc4[c] = (f32x4){0.f,0.f,0.f,0.f};
  #pragma unroll
  for (int pass = 0; pass < 4; ++pass) {
    const int dc = (eg ^ pass) * 16;      // d-chunk held by partner lane
    #pragma unroll
    for (int i = 0; i < 16; ++i) {
      const float qd = __shfl_xor(qr[i], pass);
      const f32x4* kvrow = (const f32x4*)(kvs + (dc + i)*64 + eg*16);
      #pragma unroll
      for (int c = 0; c < 4; ++c) acc4[c] += qd * kvrow[c];
    }
  }

  // pe (depthwise 3-tap conv on x) + final write
  #pragma unroll
  for (int g = 0; g < 4; ++g) {
    const int che = eg*16 + g*4;          // channel offset within head, 0..63
    const int ch  = h*64 + che;           // global channel
    f32x4 xm = (f32x4){0.f,0.f,0.f,0.f}, xp = (f32x4){0.f,0.f,0.f,0.f};
    const f32x4 xc = *(const f32x4*)(x + rowx + ch);
    if (n > 0)    xm = *(const f32x4*)(x + rowx - 1024 + ch);
    if (n < 4095) xp = *(const f32x4*)(x + rowx + 1024 + ch);
    f32x4 o;
    #pragma unroll
    for (int j = 0; j < 4; ++j) {
      const int cl = che + j;
      const float pe = lbs[cl] + xm[j]*lws[cl*3] + xc[j]*lws[cl*3+1] + xp[j]*lws[cl*3+2];
      o[j] = acc4[g][j]*z + pe;
    }
    *(f32x4*)(out + rowx + ch) = o;
  }
}

extern "C" void kernel_launch(void* const* d_in, const int* in_sizes, int n_in,
                              void* d_out, int out_size, void* d_ws, size_t ws_size,
                              hipStream_t stream) {
  const float* x   = (const float*)d_in[0];
  const float* Wqk = (const float*)d_in[1];
  const float* bqk = (const float*)d_in[2];
  const float* lw  = (const float*)d_in[3];
  const float* lb  = (const float*)d_in[4];
  float* out = (float*)d_out;

  char* ws = (char*)d_ws;
  u16* xb = (u16*)(ws);                       // 33.55 MB  x bf16
  u16* qb = (u16*)(ws + 33554432ull);         // 33.55 MB  q bf16
  u16* kb = (u16*)(ws + 67108864ull);         // 33.55 MB  k bf16
  u16* wb = (u16*)(ws + 100663296ull);        //  4.19 MB  W bf16
  float* kv = (float*)(ws + 104857600ull);    //  1.00 MB  fp32
  float* km = (float*)(ws + 105906176ull);    // 16 KB     fp32
  float* ctab = (float*)(ws + 105922560ull);  //  2 KB
  float* stab = (float*)(ws + 105924608ull);  //  2 KB

  // kv/kmean are atomically accumulated -> zero every launch (capture-safe)
  hipMemsetAsync(ws + 104857600ull, 0, 1048576ull + 16384ull, stream);
  hipLaunchKernelGGL(trig_kernel, dim3(1), dim3(512), 0, stream, ctab, stab);
  hipLaunchKernelGGL(cast_kernel, dim3(2048), dim3(256), 0, stream, x, Wqk, xb, wb);
  hipLaunchKernelGGL(gemm_kernel, dim3(128, 16), dim3(256), 0, stream, xb, wb, bqk, qb, kb);
  hipLaunchKernelGGL(kv_kernel, dim3(512), dim3(256), 0, stream, kb, xb, ctab, stab, kv, km);
  hipLaunchKernelGGL(out_kernel, dim3(64, 16, 4), dim3(256), 0, stream, qb, kv, km, x, lw, lb, ctab, stab, out);
}

// Round 5
// 394.427 us; speedup vs baseline: 6.6221x; 6.6221x over previous
//
#include <hip/hip_runtime.h>
#include <hip/hip_bf16.h>
#include <math.h>

typedef unsigned short u16;
typedef __attribute__((ext_vector_type(8))) short s16x8;
typedef __attribute__((ext_vector_type(4))) float f32x4;

#define B_ 4
#define N_ 4096
#define C_ 1024
#define M_ (B_*N_)

__device__ __forceinline__ u16 f2bf(float f) {
  unsigned u = __builtin_bit_cast(unsigned, f);
  u = u + 0x7fffu + ((u >> 16) & 1u);
  return (u16)(u >> 16);
}
__device__ __forceinline__ float bf2f(u16 h) {
  unsigned u = ((unsigned)h) << 16;
  return __builtin_bit_cast(float, u);
}

// ---------------- kernel T: one-time rope trig table (512 pairs) ----------------
__global__ void trig_kernel(float* __restrict__ ctab, float* __restrict__ stab) {
  const int i = threadIdx.x;   // 0..511
  const float theta = powf(10000.f, -(float)i * (1.f/512.f));
  ctab[i] = cosf(theta);
  stab[i] = sinf(theta);
}

// ---------------- kernel 0: fp32 -> bf16 precast of x and W ----------------
__global__ __launch_bounds__(256) void cast_kernel(
    const float* __restrict__ x, const float* __restrict__ w,
    u16* __restrict__ xb, u16* __restrict__ wb)
{
  const int NX4 = M_*C_/4;     // 4194304
  const int NW4 = 2048*C_/4;   // 524288
  int tid = blockIdx.x*256 + threadIdx.x;
  int stride = gridDim.x*256;
  for (int i = tid; i < NX4; i += stride) {
    f32x4 v = ((const f32x4*)x)[i];
    ushort4 o;
    o.x = f2bf(v[0]); o.y = f2bf(v[1]); o.z = f2bf(v[2]); o.w = f2bf(v[3]);
    ((ushort4*)xb)[i] = o;
  }
  for (int i = tid; i < NW4; i += stride) {
    f32x4 v = ((const f32x4*)w)[i];
    ushort4 o;
    o.x = f2bf(v[0]); o.y = f2bf(v[1]); o.z = f2bf(v[2]); o.w = f2bf(v[3]);
    ((ushort4*)wb)[i] = o;
  }
}

// ---------------- kernel 1: qk GEMM + bias + elu+1 + ROPE -> q_rope,k_rope (bf16) ----
// C[m,n] = sum_k xb[m,k]*wb[n,k]; epilogue: v=elu(C+bias)+1, then rope pairs via
// shfl_xor(1) (pair column lives in lane l^1). Outputs are ROPED q,k.
__global__ __launch_bounds__(256) void gemm_kernel(
    const u16* __restrict__ xb, const u16* __restrict__ wb,
    const float* __restrict__ bqk,
    const float* __restrict__ ctab, const float* __restrict__ stab,
    u16* __restrict__ qrb, u16* __restrict__ krb)
{
  __shared__ __align__(16) unsigned char As[16384];  // 128 rows x 128B (64 bf16)
  __shared__ __align__(16) unsigned char Bs[16384];
  const int t = threadIdx.x;
  const int l = t & 63;
  const int w = t >> 6;
  const int wm = w >> 1, wn = w & 1;
  const int m0 = blockIdx.x * 128;
  const int n0 = blockIdx.y * 128;

  f32x4 acc[4][4];
  #pragma unroll
  for (int a = 0; a < 4; ++a)
    #pragma unroll
    for (int b = 0; b < 4; ++b) acc[a][b] = (f32x4){0.f,0.f,0.f,0.f};

  for (int kt = 0; kt < 1024; kt += 64) {
    __syncthreads();
    #pragma unroll
    for (int i = 0; i < 4; ++i) {
      const int jc   = i*256 + t;                       // 16B chunk id 0..1023
      const int row  = jc >> 3;                         // 0..127
      const int colb = ((jc & 7) << 4) ^ ((row & 7) << 4);
      const int cole = colb >> 1;
      const int ldsoff = (i*256 + w*64) * 16;           // wave-uniform base
      __builtin_amdgcn_global_load_lds(
        (const __attribute__((address_space(1))) void*)(xb + (size_t)(m0 + row)*1024 + kt + cole),
        (__attribute__((address_space(3))) void*)(As + ldsoff), 16, 0, 0);
      __builtin_amdgcn_global_load_lds(
        (const __attribute__((address_space(1))) void*)(wb + (size_t)(n0 + row)*1024 + kt + cole),
        (__attribute__((address_space(3))) void*)(Bs + ldsoff), 16, 0, 0);
    }
    __syncthreads();

    #pragma unroll
    for (int ks = 0; ks < 2; ++ks) {
      const int kbyte = ks*64 + ((l >> 4) << 4);
      s16x8 af[4], bff[4];
      #pragma unroll
      for (int mi = 0; mi < 4; ++mi) {
        const int r = wm*64 + mi*16 + (l & 15);
        af[mi] = *(const s16x8*)(As + r*128 + (kbyte ^ ((r & 7) << 4)));
      }
      #pragma unroll
      for (int ni = 0; ni < 4; ++ni) {
        const int r = wn*64 + ni*16 + (l & 15);
        bff[ni] = *(const s16x8*)(Bs + r*128 + (kbyte ^ ((r & 7) << 4)));
      }
      #pragma unroll
      for (int mi = 0; mi < 4; ++mi)
        #pragma unroll
        for (int ni = 0; ni < 4; ++ni)
          acc[mi][ni] = __builtin_amdgcn_mfma_f32_16x16x32_bf16(af[mi], bff[ni], acc[mi][ni], 0, 0, 0);
    }
  }

  // epilogue: bias + elu+1, then rope (pair value from lane l^1), split q/k
  #pragma unroll
  for (int ni = 0; ni < 4; ++ni) {
    const int col = n0 + wn*64 + ni*16 + (l & 15);   // 0..2047
    const float bias = bqk[col];
    const int cc = col & 1023;
    const float cn = ctab[cc >> 1];
    const float sn = stab[cc >> 1];
    u16* dst = (col < 1024) ? qrb : krb;
    #pragma unroll
    for (int mi = 0; mi < 4; ++mi) {
      #pragma unroll
      for (int j = 0; j < 4; ++j) {
        const int rowm = m0 + wm*64 + mi*16 + ((l >> 4) << 2) + j;
        float v = acc[mi][ni][j] + bias;
        v = (v > 0.f) ? (v + 1.f) : __expf(v);      // elu(v)+1
        const float vp = __shfl_xor(v, 1);          // partner column (elu'd)
        const float vr = (col & 1) ? (sn*vp + cn*v) : (cn*v - sn*vp);
        dst[(size_t)rowm*1024 + cc] = f2bf(vr);
      }
    }
  }
}

// ---------------- kernel 2: kv[b,h,d,e] = mean_n kr[n,d]*v[n,e]; kmr = mean_n kr ----
__global__ __launch_bounds__(256) void kv_kernel(
    const u16* __restrict__ krb, const u16* __restrict__ xb,
    float* __restrict__ kv, float* __restrict__ kmr)
{
  const int blk = blockIdx.x;
  const int ns = blk & 7;
  const int bh = blk >> 3;             // 0..63
  const int b = bh >> 4, h = bh & 15;
  const int t = threadIdx.x;
  const int d = t >> 2;
  const int eg = t & 3;
  const int e0 = eg * 16;

  float kvacc[16];
  #pragma unroll
  for (int i = 0; i < 16; ++i) kvacc[i] = 0.f;
  float ksum = 0.f;

  const size_t base = ((size_t)b*4096 + ns*512) * 1024 + h*64;
  for (int n = 0; n < 512; ++n) {
    const size_t roff = base + (size_t)n * 1024;
    const float kr = bf2f(krb[roff + d]);    // already roped
    ksum += kr;
    const s16x8 v0 = *(const s16x8*)(xb + roff + e0);
    const s16x8 v1 = *(const s16x8*)(xb + roff + e0 + 8);
    #pragma unroll
    for (int i = 0; i < 8; ++i) kvacc[i]     += kr * bf2f((u16)v0[i]);
    #pragma unroll
    for (int i = 0; i < 8; ++i) kvacc[8 + i] += kr * bf2f((u16)v1[i]);
  }
  const float inv_n = 1.f / 4096.f;
  float* dst = kv + ((size_t)bh*64 + d)*64 + e0;
  #pragma unroll
  for (int i = 0; i < 16; ++i) atomicAdd(dst + i, kvacc[i] * inv_n);
  if (eg == 0) atomicAdd(kmr + bh*64 + d, ksum * inv_n);
}

// ---------------- kernel 2b: kv fp32 -> kvT bf16 (transposed: [bh][e][d]) ----------
__global__ __launch_bounds__(256) void kvcast_kernel(
    const float* __restrict__ kv, u16* __restrict__ kvbT)
{
  const int tid = blockIdx.x*256 + threadIdx.x;   // 262144
  const int bh = tid >> 12, r = tid & 4095, d = r >> 6, e = r & 63;
  kvbT[(bh << 12) + (e << 6) + d] = f2bf(kv[tid]);
}

// ---------------- kernel 2c: z[b][n][h] = 1/(qr . kmr + 1e-6) ----------------
// 1024 blocks x 256 threads; thread = (row 16/block, h 16)
__global__ __launch_bounds__(256) void z_kernel(
    const u16* __restrict__ qrb, const float* __restrict__ kmr,
    float* __restrict__ z)
{
  __shared__ float kms[1024];                     // transposed: kms[d*16+h]
  const int tid = blockIdx.x*256 + threadIdx.x;   // 0..262143
  const int h = tid & 15;
  const int row = tid >> 4;                       // b*4096+n
  const int b = row >> 12;
  for (int i = threadIdx.x; i < 1024; i += 256)   // i = h'*64+d
    kms[(i & 63)*16 + (i >> 6)] = kmr[b*1024 + i];
  __syncthreads();

  const u16* qrow = qrb + (size_t)row*1024 + h*64;
  float acc = 0.f;
  #pragma unroll
  for (int i = 0; i < 8; ++i) {
    const s16x8 v = *(const s16x8*)(qrow + i*8);
    #pragma unroll
    for (int j = 0; j < 8; ++j) acc += bf2f((u16)v[j]) * kms[(i*8 + j)*16 + h];
  }
  z[tid] = 1.f / (acc + 1e-6f);
}

// ---------------- kernel 3: attn MFMA: out[b,n,h*64+e] = (qr @ kv) * z ----------
// per (b,h): [4096x64] @ [64x64]. BM=128 rows/block, 4 waves (32 rows each), K=64.
__global__ __launch_bounds__(256) void attn_kernel(
    const u16* __restrict__ qrb, const u16* __restrict__ kvbT,
    const float* __restrict__ z, float* __restrict__ out)
{
  __shared__ __align__(16) unsigned char As[16384]; // 128 rows x 128B
  __shared__ __align__(16) unsigned char Bs[8192];  // 64 rows x 128B
  const int t = threadIdx.x, l = t & 63, w = t >> 6;
  const int m0 = blockIdx.x * 128;
  const int h = blockIdx.y, b = blockIdx.z;
  const size_t qbase = ((size_t)b*4096 + m0) * 1024 + h*64;
  const u16* kvsrc = kvbT + ((size_t)(b*16 + h) << 12);

  // stage A: 1024 chunks (4 iters); same swizzle discipline as gemm_kernel
  #pragma unroll
  for (int i = 0; i < 4; ++i) {
    const int jc   = i*256 + t;
    const int row  = jc >> 3;                          // 0..127
    const int cole = (((jc & 7) << 4) ^ ((row & 7) << 4)) >> 1;
    const int ldsoff = (i*256 + w*64) * 16;
    __builtin_amdgcn_global_load_lds(
      (const __attribute__((address_space(1))) void*)(qrb + qbase + (size_t)row*1024 + cole),
      (__attribute__((address_space(3))) void*)(As + ldsoff), 16, 0, 0);
  }
  // stage B: 512 chunks (2 iters)
  #pragma unroll
  for (int i = 0; i < 2; ++i) {
    const int jc   = i*256 + t;
    const int row  = jc >> 3;                          // e: 0..63
    const int cole = (((jc & 7) << 4) ^ ((row & 7) << 4)) >> 1;
    const int ldsoff = (i*256 + w*64) * 16;
    __builtin_amdgcn_global_load_lds(
      (const __attribute__((address_space(1))) void*)(kvsrc + (size_t)row*64 + cole),
      (__attribute__((address_space(3))) void*)(Bs + ldsoff), 16, 0, 0);
  }
  __syncthreads();

  f32x4 acc[2][4];
  #pragma unroll
  for (int a = 0; a < 2; ++a)
    #pragma unroll
    for (int c = 0; c < 4; ++c) acc[a][c] = (f32x4){0.f,0.f,0.f,0.f};

  #pragma unroll
  for (int ks = 0; ks < 2; ++ks) {
    const int kbyte = ks*64 + ((l >> 4) << 4);
    s16x8 af[2], bf[4];
    #pragma unroll
    for (int mi = 0; mi < 2; ++mi) {
      const int r = w*32 + mi*16 + (l & 15);
      af[mi] = *(const s16x8*)(As + r*128 + (kbyte ^ ((r & 7) << 4)));
    }
    #pragma unroll
    for (int ni = 0; ni < 4; ++ni) {
      const int r = ni*16 + (l & 15);
      bf[ni] = *(const s16x8*)(Bs + r*128 + (kbyte ^ ((r & 7) << 4)));
    }
    #pragma unroll
    for (int mi = 0; mi < 2; ++mi)
      #pragma unroll
      for (int ni = 0; ni < 4; ++ni)
        acc[mi][ni] = __builtin_amdgcn_mfma_f32_16x16x32_bf16(af[mi], bf[ni], acc[mi][ni], 0, 0, 0);
  }

  // epilogue: out = acc * z[row]
  #pragma unroll
  for (int mi = 0; mi < 2; ++mi) {
    #pragma unroll
    for (int j = 0; j < 4; ++j) {
      const int rowm = m0 + w*32 + mi*16 + ((l >> 4) << 2) + j;
      const float zr = z[((size_t)b*4096 + rowm)*16 + h];
      #pragma unroll
      for (int ni = 0; ni < 4; ++ni)
        out[((size_t)b*4096 + rowm)*1024 + h*64 + ni*16 + (l & 15)] = acc[mi][ni][j] * zr;
    }
  }
}

// ---------------- kernel 4: pe depthwise conv, out += pe (full-row streaming) ----
__global__ __launch_bounds__(256) void pe_kernel(
    const float* __restrict__ x, const float* __restrict__ lw,
    const float* __restrict__ lb, float* __restrict__ out)
{
  const int row = blockIdx.x;            // b*4096 + n
  const int n = row & 4095;
  const int t = threadIdx.x;
  const size_t base = (size_t)row * 1024 + t*4;
  const f32x4 xc = *(const f32x4*)(x + base);
  f32x4 xm = (f32x4){0.f,0.f,0.f,0.f}, xp = (f32x4){0.f,0.f,0.f,0.f};
  if (n > 0)    xm = *(const f32x4*)(x + base - 1024);
  if (n < 4095) xp = *(const f32x4*)(x + base + 1024);
  f32x4 o = *(const f32x4*)(out + base);
  #pragma unroll
  for (int j = 0; j < 4; ++j) {
    const int c = t*4 + j;
    o[j] += lb[c] + xm[j]*lw[c*3] + xc[j]*lw[c*3+1] + xp[j]*lw[c*3+2];
  }
  *(f32x4*)(out + base) = o;
}

extern "C" void kernel_launch(void* const* d_in, const int* in_sizes, int n_in,
                              void* d_out, int out_size, void* d_ws, size_t ws_size,
                              hipStream_t stream) {
  const float* x   = (const float*)d_in[0];
  const float* Wqk = (const float*)d_in[1];
  const float* bqk = (const float*)d_in[2];
  const float* lw  = (const float*)d_in[3];
  const float* lb  = (const float*)d_in[4];
  float* out = (float*)d_out;

  char* ws = (char*)d_ws;
  u16* xb    = (u16*)(ws);                       // 33.55 MB  x bf16
  u16* qrb   = (u16*)(ws + 33554432ull);         // 33.55 MB  q_rope bf16
  u16* krb   = (u16*)(ws + 67108864ull);         // 33.55 MB  k_rope bf16
  u16* wb    = (u16*)(ws + 100663296ull);        //  4.19 MB  W bf16
  float* kv  = (float*)(ws + 104857600ull);      //  1.00 MB  fp32
  float* kmr = (float*)(ws + 105906176ull);      // 16 KB     fp32
  float* ctab= (float*)(ws + 105922560ull);      //  2 KB
  float* stab= (float*)(ws + 105924608ull);      //  2 KB
  u16* kvbT  = (u16*)(ws + 105926656ull);        // 0.5 MB    kv^T bf16
  float* zb  = (float*)(ws + 106450944ull);      //  1 MB     z fp32

  // kv/kmr are atomically accumulated -> zero every launch (capture-safe)
  hipMemsetAsync(ws + 104857600ull, 0, 1064960ull, stream);
  hipLaunchKernelGGL(trig_kernel, dim3(1), dim3(512), 0, stream, ctab, stab);
  hipLaunchKernelGGL(cast_kernel, dim3(2048), dim3(256), 0, stream, x, Wqk, xb, wb);
  hipLaunchKernelGGL(gemm_kernel, dim3(128, 16), dim3(256), 0, stream, xb, wb, bqk, ctab, stab, qrb, krb);
  hipLaunchKernelGGL(kv_kernel, dim3(512), dim3(256), 0, stream, krb, xb, kv, kmr);
  hipLaunchKernelGGL(kvcast_kernel, dim3(1024), dim3(256), 0, stream, kv, kvbT);
  hipLaunchKernelGGL(z_kernel, dim3(1024), dim3(256), 0, stream, qrb, kmr, zb);
  hipLaunchKernelGGL(attn_kernel, dim3(32, 16, 4), dim3(256), 0, stream, qrb, kvbT, zb, out);
  hipLaunchKernelGGL(pe_kernel, dim3(16384), dim3(256), 0, stream, x, lw, lb, out);
}

// Round 7
// 267.804 us; speedup vs baseline: 9.7531x; 1.4728x over previous
//
#include <hip/hip_runtime.h>
#include <hip/hip_bf16.h>
#include <math.h>

typedef unsigned short u16;
typedef __attribute__((ext_vector_type(8))) short s16x8;
typedef __attribute__((ext_vector_type(4))) float f32x4;

#define B_ 4
#define N_ 4096
#define C_ 1024
#define M_ (B_*N_)

__device__ __forceinline__ u16 f2bf(float f) {
  unsigned u = __builtin_bit_cast(unsigned, f);
  u = u + 0x7fffu + ((u >> 16) & 1u);
  return (u16)(u >> 16);
}
__device__ __forceinline__ float bf2f(u16 h) {
  unsigned u = ((unsigned)h) << 16;
  return __builtin_bit_cast(float, u);
}

// ---------------- kernel T: one-time rope trig table (512 pairs) ----------------
__global__ void trig_kernel(float* __restrict__ ctab, float* __restrict__ stab) {
  const int i = threadIdx.x;   // 0..511
  const float theta = powf(10000.f, -(float)i * (1.f/512.f));
  ctab[i] = cosf(theta);
  stab[i] = sinf(theta);
}

// ---------------- kernel 0: fp32 -> bf16 precast of x and W ----------------
__global__ __launch_bounds__(256) void cast_kernel(
    const float* __restrict__ x, const float* __restrict__ w,
    u16* __restrict__ xb, u16* __restrict__ wb)
{
  const int NX4 = M_*C_/4;     // 4194304
  const int NW4 = 2048*C_/4;   // 524288
  int tid = blockIdx.x*256 + threadIdx.x;
  int stride = gridDim.x*256;
  for (int i = tid; i < NX4; i += stride) {
    f32x4 v = ((const f32x4*)x)[i];
    ushort4 o;
    o.x = f2bf(v[0]); o.y = f2bf(v[1]); o.z = f2bf(v[2]); o.w = f2bf(v[3]);
    ((ushort4*)xb)[i] = o;
  }
  for (int i = tid; i < NW4; i += stride) {
    f32x4 v = ((const f32x4*)w)[i];
    ushort4 o;
    o.x = f2bf(v[0]); o.y = f2bf(v[1]); o.z = f2bf(v[2]); o.w = f2bf(v[3]);
    ((ushort4*)wb)[i] = o;
  }
}

// ---------------- kernel 1: qk GEMM + bias + elu+1 + ROPE -> q_rope,k_rope (bf16) ----
__global__ __launch_bounds__(256) void gemm_kernel(
    const u16* __restrict__ xb, const u16* __restrict__ wb,
    const float* __restrict__ bqk,
    const float* __restrict__ ctab, const float* __restrict__ stab,
    u16* __restrict__ qrb, u16* __restrict__ krb)
{
  __shared__ __align__(16) unsigned char As[16384];  // 128 rows x 128B (64 bf16)
  __shared__ __align__(16) unsigned char Bs[16384];
  const int t = threadIdx.x;
  const int l = t & 63;
  const int w = t >> 6;
  const int wm = w >> 1, wn = w & 1;
  const int m0 = blockIdx.x * 128;
  const int n0 = blockIdx.y * 128;

  f32x4 acc[4][4];
  #pragma unroll
  for (int a = 0; a < 4; ++a)
    #pragma unroll
    for (int b = 0; b < 4; ++b) acc[a][b] = (f32x4){0.f,0.f,0.f,0.f};

  for (int kt = 0; kt < 1024; kt += 64) {
    __syncthreads();
    #pragma unroll
    for (int i = 0; i < 4; ++i) {
      const int jc   = i*256 + t;                       // 16B chunk id 0..1023
      const int row  = jc >> 3;                         // 0..127
      const int colb = ((jc & 7) << 4) ^ ((row & 7) << 4);
      const int cole = colb >> 1;
      const int ldsoff = (i*256 + w*64) * 16;           // wave-uniform base
      __builtin_amdgcn_global_load_lds(
        (const __attribute__((address_space(1))) void*)(xb + (size_t)(m0 + row)*1024 + kt + cole),
        (__attribute__((address_space(3))) void*)(As + ldsoff), 16, 0, 0);
      __builtin_amdgcn_global_load_lds(
        (const __attribute__((address_space(1))) void*)(wb + (size_t)(n0 + row)*1024 + kt + cole),
        (__attribute__((address_space(3))) void*)(Bs + ldsoff), 16, 0, 0);
    }
    __syncthreads();

    #pragma unroll
    for (int ks = 0; ks < 2; ++ks) {
      const int kbyte = ks*64 + ((l >> 4) << 4);
      s16x8 af[4], bff[4];
      #pragma unroll
      for (int mi = 0; mi < 4; ++mi) {
        const int r = wm*64 + mi*16 + (l & 15);
        af[mi] = *(const s16x8*)(As + r*128 + (kbyte ^ ((r & 7) << 4)));
      }
      #pragma unroll
      for (int ni = 0; ni < 4; ++ni) {
        const int r = wn*64 + ni*16 + (l & 15);
        bff[ni] = *(const s16x8*)(Bs + r*128 + (kbyte ^ ((r & 7) << 4)));
      }
      #pragma unroll
      for (int mi = 0; mi < 4; ++mi)
        #pragma unroll
        for (int ni = 0; ni < 4; ++ni)
          acc[mi][ni] = __builtin_amdgcn_mfma_f32_16x16x32_bf16(af[mi], bff[ni], acc[mi][ni], 0, 0, 0);
    }
  }

  // epilogue: bias + elu+1, then rope (pair value from lane l^1), split q/k
  #pragma unroll
  for (int ni = 0; ni < 4; ++ni) {
    const int col = n0 + wn*64 + ni*16 + (l & 15);   // 0..2047
    const float bias = bqk[col];
    const int cc = col & 1023;
    const float cn = ctab[cc >> 1];
    const float sn = stab[cc >> 1];
    u16* dst = (col < 1024) ? qrb : krb;
    #pragma unroll
    for (int mi = 0; mi < 4; ++mi) {
      #pragma unroll
      for (int j = 0; j < 4; ++j) {
        const int rowm = m0 + wm*64 + mi*16 + ((l >> 4) << 2) + j;
        float v = acc[mi][ni][j] + bias;
        v = (v > 0.f) ? (v + 1.f) : __expf(v);      // elu(v)+1
        const float vp = __shfl_xor(v, 1);          // partner column (elu'd)
        const float vr = (col & 1) ? (sn*vp + cn*v) : (cn*v - sn*vp);
        dst[(size_t)rowm*1024 + cc] = f2bf(vr);
      }
    }
  }
}

// ---------------- kernel 2: kv partials: 8d x 8e per thread, 16 n-slices ----------
// grid 1024 = bh(64) x ns(16); block 256 = nsub(4 waves) x dg(8) x eg(8)
// partial[ns][bh][d][e] (fp32, RAW sums) lands in d_out scratch; kmr via atomics.
__global__ __launch_bounds__(256, 4) void kvpart_kernel(
    const u16* __restrict__ krb, const u16* __restrict__ xb,
    float* __restrict__ partial, float* __restrict__ kmr)
{
  __shared__ float red[2][64][65];   // odd stride: conflict-free lane columns
  const int t = threadIdx.x;
  const int l = t & 63;
  const int nsub = t >> 6;
  const int dg = l >> 3, eg = l & 7;
  const int d0 = dg*8, e0 = eg*8;
  const int blk = blockIdx.x;
  const int bh = blk >> 4;
  const int ns = blk & 15;
  const int b = bh >> 4, h = bh & 15;

  float acc[8][8];
  #pragma unroll
  for (int i=0;i<8;++i)
    #pragma unroll
    for (int j=0;j<8;++j) acc[i][j]=0.f;
  float ksum[8];
  #pragma unroll
  for (int i=0;i<8;++i) ksum[i]=0.f;

  const size_t base = ((size_t)b*4096 + ns*256 + nsub*64) * 1024 + h*64;
  #pragma unroll 2
  for (int it = 0; it < 64; ++it) {
    const size_t roff = base + (size_t)it*1024;
    const s16x8 k8 = *(const s16x8*)(krb + roff + d0);
    const s16x8 v8 = *(const s16x8*)(xb + roff + e0);
    float kf[8], vf[8];
    #pragma unroll
    for (int i=0;i<8;++i){ kf[i]=bf2f((u16)k8[i]); vf[i]=bf2f((u16)v8[i]); }
    #pragma unroll
    for (int i=0;i<8;++i){
      ksum[i]+=kf[i];
      #pragma unroll
      for (int j=0;j<8;++j) acc[i][j] += kf[i]*vf[j];
    }
  }

  // cross-wave (nsub) tree reduction via LDS
  if (nsub >= 2) {
    #pragma unroll
    for (int i=0;i<8;++i)
      #pragma unroll
      for (int j=0;j<8;++j) red[nsub-2][l][i*8+j] = acc[i][j];
  }
  __syncthreads();
  if (nsub < 2) {
    #pragma unroll
    for (int i=0;i<8;++i)
      #pragma unroll
      for (int j=0;j<8;++j) acc[i][j] += red[nsub][l][i*8+j];
  }
  __syncthreads();
  if (nsub == 1) {
    #pragma unroll
    for (int i=0;i<8;++i)
      #pragma unroll
      for (int j=0;j<8;++j) red[0][l][i*8+j] = acc[i][j];
  }
  __syncthreads();
  if (nsub == 0) {
    float* dst = partial + ((size_t)ns*64 + bh)*4096 + d0*64 + e0;
    #pragma unroll
    for (int i=0;i<8;++i) {
      f32x4 lo, hi;
      #pragma unroll
      for (int j=0;j<4;++j) { lo[j] = acc[i][j] + red[0][l][i*8+j];
                              hi[j] = acc[i][j+4] + red[0][l][i*8+j+4]; }
      *(f32x4*)(dst + i*64)     = lo;
      *(f32x4*)(dst + i*64 + 4) = hi;
    }
  }
  // kmr: ksum identical across eg; each wave adds its own 64-n contribution
  if (eg == 0) {
    #pragma unroll
    for (int i=0;i<8;++i)
      atomicAdd(kmr + bh*64 + d0 + i, ksum[i] * (1.f/4096.f));
  }
}

// ---------------- kernel 2b: sum 16 partial slices, *1/n, transpose -> kvbT bf16 ----
__global__ __launch_bounds__(256) void kvred_kernel(
    const float* __restrict__ partial, u16* __restrict__ kvbT)
{
  __shared__ float s[4096];
  const int bh = blockIdx.x;
  const int t = threadIdx.x;
  f32x4 a0={0,0,0,0}, a1={0,0,0,0}, a2={0,0,0,0}, a3={0,0,0,0};
  #pragma unroll
  for (int sl=0; sl<16; ++sl) {
    const f32x4* p = (const f32x4*)(partial + ((size_t)sl*64 + bh)*4096 + t*16);
    a0 += p[0]; a1 += p[1]; a2 += p[2]; a3 += p[3];
  }
  ((f32x4*)s)[t*4+0]=a0; ((f32x4*)s)[t*4+1]=a1;
  ((f32x4*)s)[t*4+2]=a2; ((f32x4*)s)[t*4+3]=a3;
  __syncthreads();
  // out elems [t*16, t*16+16): e = t>>2 fixed, d = (t&3)*16 + j
  // R6 bug fix: apply the reference's 1/n scaling here (was missing -> absmax 233)
  const float inv_n = 1.f / 4096.f;
  s16x8 o0, o1;
  #pragma unroll
  for (int j=0;j<8;++j) {
    o0[j] = (short)f2bf(s[((t&3)*16 + j)*64 + (t>>2)] * inv_n);
    o1[j] = (short)f2bf(s[((t&3)*16 + 8 + j)*64 + (t>>2)] * inv_n);
  }
  *(s16x8*)(kvbT + (size_t)bh*4096 + t*16) = o0;
  *(s16x8*)(kvbT + (size_t)bh*4096 + t*16 + 8) = o1;
}

// ---------------- kernel 2c: z[b][n][h] = 1/(qr . kmr + 1e-6) ----------------
__global__ __launch_bounds__(256) void z_kernel(
    const u16* __restrict__ qrb, const float* __restrict__ kmr,
    float* __restrict__ z)
{
  __shared__ float kms[1024];                     // transposed: kms[d*16+h]
  const int tid = blockIdx.x*256 + threadIdx.x;   // 0..262143
  const int h = tid & 15;
  const int row = tid >> 4;                       // b*4096+n
  const int b = row >> 12;
  for (int i = threadIdx.x; i < 1024; i += 256)   // i = h'*64+d
    kms[(i & 63)*16 + (i >> 6)] = kmr[b*1024 + i];
  __syncthreads();

  const u16* qrow = qrb + (size_t)row*1024 + h*64;
  float acc = 0.f;
  #pragma unroll
  for (int i = 0; i < 8; ++i) {
    const s16x8 v = *(const s16x8*)(qrow + i*8);
    #pragma unroll
    for (int j = 0; j < 8; ++j) acc += bf2f((u16)v[j]) * kms[(i*8 + j)*16 + h];
  }
  z[tid] = 1.f / (acc + 1e-6f);
}

// ---------------- kernel 3: attn MFMA + z scale + fused pe conv ----------------
// per (b,h): [4096x64] @ [64x64]. BM=128 rows/block, 4 waves, K=64.
__global__ __launch_bounds__(256) void attn_kernel(
    const u16* __restrict__ qrb, const u16* __restrict__ kvbT,
    const float* __restrict__ z, const float* __restrict__ x,
    const float* __restrict__ lw, const float* __restrict__ lb,
    float* __restrict__ out)
{
  __shared__ __align__(16) unsigned char As[16384]; // 128 rows x 128B
  __shared__ __align__(16) unsigned char Bs[8192];  // 64 rows x 128B
  __shared__ float lws[192], lbs[64];
  const int t = threadIdx.x, l = t & 63, w = t >> 6;
  const int m0 = blockIdx.x * 128;
  const int h = blockIdx.y, b = blockIdx.z;
  const size_t qbase = ((size_t)b*4096 + m0) * 1024 + h*64;
  const u16* kvsrc = kvbT + ((size_t)(b*16 + h) << 12);

  #pragma unroll
  for (int i = 0; i < 4; ++i) {
    const int jc   = i*256 + t;
    const int row  = jc >> 3;                          // 0..127
    const int cole = (((jc & 7) << 4) ^ ((row & 7) << 4)) >> 1;
    const int ldsoff = (i*256 + w*64) * 16;
    __builtin_amdgcn_global_load_lds(
      (const __attribute__((address_space(1))) void*)(qrb + qbase + (size_t)row*1024 + cole),
      (__attribute__((address_space(3))) void*)(As + ldsoff), 16, 0, 0);
  }
  #pragma unroll
  for (int i = 0; i < 2; ++i) {
    const int jc   = i*256 + t;
    const int row  = jc >> 3;                          // e: 0..63
    const int cole = (((jc & 7) << 4) ^ ((row & 7) << 4)) >> 1;
    const int ldsoff = (i*256 + w*64) * 16;
    __builtin_amdgcn_global_load_lds(
      (const __attribute__((address_space(1))) void*)(kvsrc + (size_t)row*64 + cole),
      (__attribute__((address_space(3))) void*)(Bs + ldsoff), 16, 0, 0);
  }
  if (t < 192) lws[t] = lw[h*192 + t];
  if (t >= 192)  lbs[t-192] = lb[h*64 + (t-192)];
  __syncthreads();

  f32x4 acc[2][4];
  #pragma unroll
  for (int a = 0; a < 2; ++a)
    #pragma unroll
    for (int c = 0; c < 4; ++c) acc[a][c] = (f32x4){0.f,0.f,0.f,0.f};

  #pragma unroll
  for (int ks = 0; ks < 2; ++ks) {
    const int kbyte = ks*64 + ((l >> 4) << 4);
    s16x8 af[2], bf[4];
    #pragma unroll
    for (int mi = 0; mi < 2; ++mi) {
      const int r = w*32 + mi*16 + (l & 15);
      af[mi] = *(const s16x8*)(As + r*128 + (kbyte ^ ((r & 7) << 4)));
    }
    #pragma unroll
    for (int ni = 0; ni < 4; ++ni) {
      const int r = ni*16 + (l & 15);
      bf[ni] = *(const s16x8*)(Bs + r*128 + (kbyte ^ ((r & 7) << 4)));
    }
    #pragma unroll
    for (int mi = 0; mi < 2; ++mi)
      #pragma unroll
      for (int ni = 0; ni < 4; ++ni)
        acc[mi][ni] = __builtin_amdgcn_mfma_f32_16x16x32_bf16(af[mi], bf[ni], acc[mi][ni], 0, 0, 0);
  }

  // epilogue: out = acc * z[row] + pe(x)
  #pragma unroll
  for (int mi = 0; mi < 2; ++mi) {
    #pragma unroll
    for (int j = 0; j < 4; ++j) {
      const int rowm = m0 + w*32 + mi*16 + ((l >> 4) << 2) + j;
      const float zr = z[((size_t)b*4096 + rowm)*16 + h];
      const size_t rbase = ((size_t)b*4096 + rowm)*1024;
      #pragma unroll
      for (int ni = 0; ni < 4; ++ni) {
        const int cl = ni*16 + (l & 15);       // in-head channel 0..63
        const int c = h*64 + cl;
        float pe = lbs[cl] + x[rbase + c]*lws[cl*3+1];
        if (rowm > 0)    pe += x[rbase - 1024 + c]*lws[cl*3];
        if (rowm < 4095) pe += x[rbase + 1024 + c]*lws[cl*3+2];
        out[rbase + c] = acc[mi][ni][j]*zr + pe;
      }
    }
  }
}

extern "C" void kernel_launch(void* const* d_in, const int* in_sizes, int n_in,
                              void* d_out, int out_size, void* d_ws, size_t ws_size,
                              hipStream_t stream) {
  const float* x   = (const float*)d_in[0];
  const float* Wqk = (const float*)d_in[1];
  const float* bqk = (const float*)d_in[2];
  const float* lw  = (const float*)d_in[3];
  const float* lb  = (const float*)d_in[4];
  float* out = (float*)d_out;

  char* ws = (char*)d_ws;
  u16* xb    = (u16*)(ws);                       // 33.55 MB  x bf16
  u16* qrb   = (u16*)(ws + 33554432ull);         // 33.55 MB  q_rope bf16
  u16* krb   = (u16*)(ws + 67108864ull);         // 33.55 MB  k_rope bf16
  u16* wb    = (u16*)(ws + 100663296ull);        //  4.19 MB  W bf16
  float* kmr = (float*)(ws + 104857600ull);      // 16 KB     fp32
  float* ctab= (float*)(ws + 104874368ull);      //  2 KB
  float* stab= (float*)(ws + 104876416ull);      //  2 KB
  u16* kvbT  = (u16*)(ws + 104878464ull);        // 0.5 MB    kv^T bf16
  float* zb  = (float*)(ws + 105402752ull);      //  1 MB     z fp32
  // kv partials (16.8 MB fp32) live in d_out scratch; attn overwrites all of out later.
  float* partial = out;

  hipMemsetAsync(kmr, 0, 16384ull, stream);      // atomic target only
  hipLaunchKernelGGL(trig_kernel, dim3(1), dim3(512), 0, stream, ctab, stab);
  hipLaunchKernelGGL(cast_kernel, dim3(2048), dim3(256), 0, stream, x, Wqk, xb, wb);
  hipLaunchKernelGGL(gemm_kernel, dim3(128, 16), dim3(256), 0, stream, xb, wb, bqk, ctab, stab, qrb, krb);
  hipLaunchKernelGGL(kvpart_kernel, dim3(1024), dim3(256), 0, stream, krb, xb, partial, kmr);
  hipLaunchKernelGGL(kvred_kernel, dim3(64), dim3(256), 0, stream, partial, kvbT);
  hipLaunchKernelGGL(z_kernel, dim3(1024), dim3(256), 0, stream, qrb, kmr, zb);
  hipLaunchKernelGGL(attn_kernel, dim3(32, 16, 4), dim3(256), 0, stream, qrb, kvbT, zb, x, lw, lb, out);
}

// Round 8
// 256.275 us; speedup vs baseline: 10.1919x; 1.0450x over previous
//
#include <hip/hip_runtime.h>
#include <hip/hip_bf16.h>
#include <math.h>

typedef unsigned short u16;
typedef __attribute__((ext_vector_type(8))) short s16x8;
typedef __attribute__((ext_vector_type(4))) float f32x4;

#define B_ 4
#define N_ 4096
#define C_ 1024
#define M_ (B_*N_)
#define NT_ 16   // K / 64

__device__ __forceinline__ u16 f2bf(float f) {
  unsigned u = __builtin_bit_cast(unsigned, f);
  u = u + 0x7fffu + ((u >> 16) & 1u);
  return (u16)(u >> 16);
}
__device__ __forceinline__ float bf2f(u16 h) {
  unsigned u = ((unsigned)h) << 16;
  return __builtin_bit_cast(float, u);
}

// ---------------- kernel T: one-time rope trig table (512 pairs) ----------------
__global__ void trig_kernel(float* __restrict__ ctab, float* __restrict__ stab) {
  const int i = threadIdx.x;   // 0..511
  const float theta = powf(10000.f, -(float)i * (1.f/512.f));
  ctab[i] = cosf(theta);
  stab[i] = sinf(theta);
}

// ---------------- kernel 0: fp32 -> bf16 precast of x and W ----------------
__global__ __launch_bounds__(256) void cast_kernel(
    const float* __restrict__ x, const float* __restrict__ w,
    u16* __restrict__ xb, u16* __restrict__ wb)
{
  const int NX4 = M_*C_/4;     // 4194304
  const int NW4 = 2048*C_/4;   // 524288
  int tid = blockIdx.x*256 + threadIdx.x;
  int stride = gridDim.x*256;
  for (int i = tid; i < NX4; i += stride) {
    f32x4 v = ((const f32x4*)x)[i];
    ushort4 o;
    o.x = f2bf(v[0]); o.y = f2bf(v[1]); o.z = f2bf(v[2]); o.w = f2bf(v[3]);
    ((ushort4*)xb)[i] = o;
  }
  for (int i = tid; i < NW4; i += stride) {
    f32x4 v = ((const f32x4*)w)[i];
    ushort4 o;
    o.x = f2bf(v[0]); o.y = f2bf(v[1]); o.z = f2bf(v[2]); o.w = f2bf(v[3]);
    ((ushort4*)wb)[i] = o;
  }
}

// ---------------- kernel 1: qk GEMM + bias + elu+1 + ROPE -> q_rope,k_rope ----
// 256x256 tile, BK=64, 8 waves (2M x 4N), per-wave 128x64, double-buffered LDS,
// prefetch kt+1 at phase 0, counted-drain (vmcnt(0) once per K-tile at group end),
// 4 phases x {4 ds_read | barrier | setprio(1) 16 MFMA setprio(0) | barrier}.
__global__ __launch_bounds__(512, 2) void gemm_kernel(
    const u16* __restrict__ xb, const u16* __restrict__ wb,
    const float* __restrict__ bqk,
    const float* __restrict__ ctab, const float* __restrict__ stab,
    u16* __restrict__ qrb, u16* __restrict__ krb)
{
  __shared__ __align__(16) unsigned char As[2][32768];  // [buf][256 rows][128B]
  __shared__ __align__(16) unsigned char Bs[2][32768];
  const int t = threadIdx.x;             // 0..511
  const int l = t & 63;
  const int w = t >> 6;                  // 0..7
  const int wm = w >> 2, wn = w & 3;     // 2M x 4N
  const int m0 = blockIdx.x * 256;
  const int n0 = blockIdx.y * 256;

  f32x4 acc[8][4];
  #pragma unroll
  for (int a = 0; a < 8; ++a)
    #pragma unroll
    for (int b = 0; b < 4; ++b) acc[a][b] = (f32x4){0.f,0.f,0.f,0.f};

  // staging: chunk jc = i*512 + t; row = jc>>3 = i*64 + (t>>3); col-chunk (t&7)
  // pre-swizzled source col (involution with read-side XOR): (t&7)^(row&7)
  const int s_row  = t >> 3;                               // 0..63
  const int s_cole = ((t & 7) ^ ((t >> 3) & 7)) << 3;      // element offset 0..56
  const size_t a_base = (size_t)(m0 + s_row) * 1024 + s_cole;
  const size_t b_base = (size_t)(n0 + s_row) * 1024 + s_cole;

  #define STAGE(buf, kt) do {                                                  \
    const int ko_ = (kt) * 64;                                                 \
    _Pragma("unroll")                                                          \
    for (int i_ = 0; i_ < 4; ++i_) {                                           \
      __builtin_amdgcn_global_load_lds(                                        \
        (const __attribute__((address_space(1))) void*)(xb + a_base + (size_t)i_*65536 + ko_), \
        (__attribute__((address_space(3))) void*)(&As[buf][(i_*512 + w*64)*16]), 16, 0, 0); \
    }                                                                          \
    _Pragma("unroll")                                                          \
    for (int i_ = 0; i_ < 4; ++i_) {                                           \
      __builtin_amdgcn_global_load_lds(                                        \
        (const __attribute__((address_space(1))) void*)(wb + b_base + (size_t)i_*65536 + ko_), \
        (__attribute__((address_space(3))) void*)(&Bs[buf][(i_*512 + w*64)*16]), 16, 0, 0); \
    }                                                                          \
  } while (0)

  // prologue: stage kt=0, full drain
  STAGE(0, 0);
  asm volatile("s_waitcnt vmcnt(0)" ::: "memory");
  __builtin_amdgcn_s_barrier();

  for (int kt = 0; kt < NT_; ++kt) {
    const int cur = kt & 1;
    const unsigned char* Ab = As[cur];
    const unsigned char* Bb = Bs[cur];
    s16x8 bfr[4][2];
    #pragma unroll
    for (int p = 0; p < 4; ++p) {
      // ds-load this phase's A-subtile (2 m-frags x 2 ks)
      s16x8 af[2][2];
      #pragma unroll
      for (int f = 0; f < 2; ++f) {
        const int r = wm*128 + (2*p + f)*16 + (l & 15);
        #pragma unroll
        for (int ks = 0; ks < 2; ++ks) {
          const int kbyte = ks*64 + ((l >> 4) << 4);
          af[f][ks] = *(const s16x8*)(Ab + r*128 + (kbyte ^ ((r & 7) << 4)));
        }
      }
      if (p == 0) {
        // B fragments for the whole K-tile (held in regs across phases)
        #pragma unroll
        for (int nf = 0; nf < 4; ++nf) {
          const int r = wn*64 + nf*16 + (l & 15);
          #pragma unroll
          for (int ks = 0; ks < 2; ++ks) {
            const int kbyte = ks*64 + ((l >> 4) << 4);
            bfr[nf][ks] = *(const s16x8*)(Bb + r*128 + (kbyte ^ ((r & 7) << 4)));
          }
        }
        // front-load next K-tile's staging (other buffer; race-free)
        if (kt + 1 < NT_) STAGE(cur ^ 1, kt + 1);
      }
      __builtin_amdgcn_s_barrier();
      __builtin_amdgcn_s_setprio(1);
      #pragma unroll
      for (int f = 0; f < 2; ++f)
        #pragma unroll
        for (int nf = 0; nf < 4; ++nf)
          #pragma unroll
          for (int ks = 0; ks < 2; ++ks)
            acc[2*p + f][nf] = __builtin_amdgcn_mfma_f32_16x16x32_bf16(
                af[f][ks], bfr[nf][ks], acc[2*p + f][nf], 0, 0, 0);
      __builtin_amdgcn_s_setprio(0);
      if (p == 3) asm volatile("s_waitcnt vmcnt(0)" ::: "memory");  // kt+1 arrived
      __builtin_amdgcn_s_barrier();
    }
  }
  #undef STAGE

  // epilogue: bias + elu+1, rope via shfl_xor(1), split q/k (block-uniform)
  #pragma unroll
  for (int nf = 0; nf < 4; ++nf) {
    const int col = n0 + wn*64 + nf*16 + (l & 15);   // 0..2047
    const float bias = bqk[col];
    const int cc = col & 1023;
    const float cn = ctab[cc >> 1];
    const float sn = stab[cc >> 1];
    u16* dst = (col < 1024) ? qrb : krb;
    #pragma unroll
    for (int mf = 0; mf < 8; ++mf) {
      #pragma unroll
      for (int j = 0; j < 4; ++j) {
        const int rowm = m0 + wm*128 + mf*16 + ((l >> 4) << 2) + j;
        float v = acc[mf][nf][j] + bias;
        v = (v > 0.f) ? (v + 1.f) : __expf(v);      // elu(v)+1
        const float vp = __shfl_xor(v, 1);          // partner column (elu'd)
        const float vr = (col & 1) ? (sn*vp + cn*v) : (cn*v - sn*vp);
        dst[(size_t)rowm*1024 + cc] = f2bf(vr);
      }
    }
  }
}

// ---------------- kernel 2: kv partials: 8d x 8e per thread, 16 n-slices ----------
// grid 1024 = bh(64) x ns(16); block 256 = nsub(4 waves) x dg(8) x eg(8)
// partial[ns][bh][d][e] (fp32, RAW sums) lands in d_out scratch; kmr via atomics.
__global__ __launch_bounds__(256, 4) void kvpart_kernel(
    const u16* __restrict__ krb, const u16* __restrict__ xb,
    float* __restrict__ partial, float* __restrict__ kmr)
{
  __shared__ float red[2][64][65];   // odd stride: conflict-free lane columns
  const int t = threadIdx.x;
  const int l = t & 63;
  const int nsub = t >> 6;
  const int dg = l >> 3, eg = l & 7;
  const int d0 = dg*8, e0 = eg*8;
  const int blk = blockIdx.x;
  const int bh = blk >> 4;
  const int ns = blk & 15;
  const int b = bh >> 4, h = bh & 15;

  float acc[8][8];
  #pragma unroll
  for (int i=0;i<8;++i)
    #pragma unroll
    for (int j=0;j<8;++j) acc[i][j]=0.f;
  float ksum[8];
  #pragma unroll
  for (int i=0;i<8;++i) ksum[i]=0.f;

  const size_t base = ((size_t)b*4096 + ns*256 + nsub*64) * 1024 + h*64;
  #pragma unroll 2
  for (int it = 0; it < 64; ++it) {
    const size_t roff = base + (size_t)it*1024;
    const s16x8 k8 = *(const s16x8*)(krb + roff + d0);
    const s16x8 v8 = *(const s16x8*)(xb + roff + e0);
    float kf[8], vf[8];
    #pragma unroll
    for (int i=0;i<8;++i){ kf[i]=bf2f((u16)k8[i]); vf[i]=bf2f((u16)v8[i]); }
    #pragma unroll
    for (int i=0;i<8;++i){
      ksum[i]+=kf[i];
      #pragma unroll
      for (int j=0;j<8;++j) acc[i][j] += kf[i]*vf[j];
    }
  }

  // cross-wave (nsub) tree reduction via LDS
  if (nsub >= 2) {
    #pragma unroll
    for (int i=0;i<8;++i)
      #pragma unroll
      for (int j=0;j<8;++j) red[nsub-2][l][i*8+j] = acc[i][j];
  }
  __syncthreads();
  if (nsub < 2) {
    #pragma unroll
    for (int i=0;i<8;++i)
      #pragma unroll
      for (int j=0;j<8;++j) acc[i][j] += red[nsub][l][i*8+j];
  }
  __syncthreads();
  if (nsub == 1) {
    #pragma unroll
    for (int i=0;i<8;++i)
      #pragma unroll
      for (int j=0;j<8;++j) red[0][l][i*8+j] = acc[i][j];
  }
  __syncthreads();
  if (nsub == 0) {
    float* dst = partial + ((size_t)ns*64 + bh)*4096 + d0*64 + e0;
    #pragma unroll
    for (int i=0;i<8;++i) {
      f32x4 lo, hi;
      #pragma unroll
      for (int j=0;j<4;++j) { lo[j] = acc[i][j] + red[0][l][i*8+j];
                              hi[j] = acc[i][j+4] + red[0][l][i*8+j+4]; }
      *(f32x4*)(dst + i*64)     = lo;
      *(f32x4*)(dst + i*64 + 4) = hi;
    }
  }
  // kmr: ksum identical across eg; each wave adds its own 64-n contribution
  if (eg == 0) {
    #pragma unroll
    for (int i=0;i<8;++i)
      atomicAdd(kmr + bh*64 + d0 + i, ksum[i] * (1.f/4096.f));
  }
}

// ---------------- kernel 2b: sum 16 partial slices, *1/n, transpose -> kvbT bf16 ----
__global__ __launch_bounds__(256) void kvred_kernel(
    const float* __restrict__ partial, u16* __restrict__ kvbT)
{
  __shared__ float s[4096];
  const int bh = blockIdx.x;
  const int t = threadIdx.x;
  f32x4 a0={0,0,0,0}, a1={0,0,0,0}, a2={0,0,0,0}, a3={0,0,0,0};
  #pragma unroll
  for (int sl=0; sl<16; ++sl) {
    const f32x4* p = (const f32x4*)(partial + ((size_t)sl*64 + bh)*4096 + t*16);
    a0 += p[0]; a1 += p[1]; a2 += p[2]; a3 += p[3];
  }
  ((f32x4*)s)[t*4+0]=a0; ((f32x4*)s)[t*4+1]=a1;
  ((f32x4*)s)[t*4+2]=a2; ((f32x4*)s)[t*4+3]=a3;
  __syncthreads();
  // out elems [t*16, t*16+16): e = t>>2 fixed, d = (t&3)*16 + j
  const float inv_n = 1.f / 4096.f;
  s16x8 o0, o1;
  #pragma unroll
  for (int j=0;j<8;++j) {
    o0[j] = (short)f2bf(s[((t&3)*16 + j)*64 + (t>>2)] * inv_n);
    o1[j] = (short)f2bf(s[((t&3)*16 + 8 + j)*64 + (t>>2)] * inv_n);
  }
  *(s16x8*)(kvbT + (size_t)bh*4096 + t*16) = o0;
  *(s16x8*)(kvbT + (size_t)bh*4096 + t*16 + 8) = o1;
}

// ---------------- kernel 2c: z[b][n][h] = 1/(qr . kmr + 1e-6) ----------------
__global__ __launch_bounds__(256) void z_kernel(
    const u16* __restrict__ qrb, const float* __restrict__ kmr,
    float* __restrict__ z)
{
  __shared__ float kms[1024];                     // transposed: kms[d*16+h]
  const int tid = blockIdx.x*256 + threadIdx.x;   // 0..262143
  const int h = tid & 15;
  const int row = tid >> 4;                       // b*4096+n
  const int b = row >> 12;
  for (int i = threadIdx.x; i < 1024; i += 256)   // i = h'*64+d
    kms[(i & 63)*16 + (i >> 6)] = kmr[b*1024 + i];
  __syncthreads();

  const u16* qrow = qrb + (size_t)row*1024 + h*64;
  float acc = 0.f;
  #pragma unroll
  for (int i = 0; i < 8; ++i) {
    const s16x8 v = *(const s16x8*)(qrow + i*8);
    #pragma unroll
    for (int j = 0; j < 8; ++j) acc += bf2f((u16)v[j]) * kms[(i*8 + j)*16 + h];
  }
  z[tid] = 1.f / (acc + 1e-6f);
}

// ---------------- kernel 3: attn MFMA + z scale + fused pe conv ----------------
// per (b,h): [4096x64] @ [64x64]. BM=128 rows/block, 4 waves, K=64.
__global__ __launch_bounds__(256) void attn_kernel(
    const u16* __restrict__ qrb, const u16* __restrict__ kvbT,
    const float* __restrict__ z, const float* __restrict__ x,
    const float* __restrict__ lw, const float* __restrict__ lb,
    float* __restrict__ out)
{
  __shared__ __align__(16) unsigned char As[16384]; // 128 rows x 128B
  __shared__ __align__(16) unsigned char Bs[8192];  // 64 rows x 128B
  __shared__ float lws[192], lbs[64];
  const int t = threadIdx.x, l = t & 63, w = t >> 6;
  const int m0 = blockIdx.x * 128;
  const int h = blockIdx.y, b = blockIdx.z;
  const size_t qbase = ((size_t)b*4096 + m0) * 1024 + h*64;
  const u16* kvsrc = kvbT + ((size_t)(b*16 + h) << 12);

  #pragma unroll
  for (int i = 0; i < 4; ++i) {
    const int jc   = i*256 + t;
    const int row  = jc >> 3;                          // 0..127
    const int cole = (((jc & 7) << 4) ^ ((row & 7) << 4)) >> 1;
    const int ldsoff = (i*256 + w*64) * 16;
    __builtin_amdgcn_global_load_lds(
      (const __attribute__((address_space(1))) void*)(qrb + qbase + (size_t)row*1024 + cole),
      (__attribute__((address_space(3))) void*)(As + ldsoff), 16, 0, 0);
  }
  #pragma unroll
  for (int i = 0; i < 2; ++i) {
    const int jc   = i*256 + t;
    const int row  = jc >> 3;                          // e: 0..63
    const int cole = (((jc & 7) << 4) ^ ((row & 7) << 4)) >> 1;
    const int ldsoff = (i*256 + w*64) * 16;
    __builtin_amdgcn_global_load_lds(
      (const __attribute__((address_space(1))) void*)(kvsrc + (size_t)row*64 + cole),
      (__attribute__((address_space(3))) void*)(Bs + ldsoff), 16, 0, 0);
  }
  if (t < 192) lws[t] = lw[h*192 + t];
  if (t >= 192)  lbs[t-192] = lb[h*64 + (t-192)];
  __syncthreads();

  f32x4 acc[2][4];
  #pragma unroll
  for (int a = 0; a < 2; ++a)
    #pragma unroll
    for (int c = 0; c < 4; ++c) acc[a][c] = (f32x4){0.f,0.f,0.f,0.f};

  #pragma unroll
  for (int ks = 0; ks < 2; ++ks) {
    const int kbyte = ks*64 + ((l >> 4) << 4);
    s16x8 af[2], bf[4];
    #pragma unroll
    for (int mi = 0; mi < 2; ++mi) {
      const int r = w*32 + mi*16 + (l & 15);
      af[mi] = *(const s16x8*)(As + r*128 + (kbyte ^ ((r & 7) << 4)));
    }
    #pragma unroll
    for (int ni = 0; ni < 4; ++ni) {
      const int r = ni*16 + (l & 15);
      bf[ni] = *(const s16x8*)(Bs + r*128 + (kbyte ^ ((r & 7) << 4)));
    }
    #pragma unroll
    for (int mi = 0; mi < 2; ++mi)
      #pragma unroll
      for (int ni = 0; ni < 4; ++ni)
        acc[mi][ni] = __builtin_amdgcn_mfma_f32_16x16x32_bf16(af[mi], bf[ni], acc[mi][ni], 0, 0, 0);
  }

  // epilogue: out = acc * z[row] + pe(x)
  #pragma unroll
  for (int mi = 0; mi < 2; ++mi) {
    #pragma unroll
    for (int j = 0; j < 4; ++j) {
      const int rowm = m0 + w*32 + mi*16 + ((l >> 4) << 2) + j;
      const float zr = z[((size_t)b*4096 + rowm)*16 + h];
      const size_t rbase = ((size_t)b*4096 + rowm)*1024;
      #pragma unroll
      for (int ni = 0; ni < 4; ++ni) {
        const int cl = ni*16 + (l & 15);       // in-head channel 0..63
        const int c = h*64 + cl;
        float pe = lbs[cl] + x[rbase + c]*lws[cl*3+1];
        if (rowm > 0)    pe += x[rbase - 1024 + c]*lws[cl*3];
        if (rowm < 4095) pe += x[rbase + 1024 + c]*lws[cl*3+2];
        out[rbase + c] = acc[mi][ni][j]*zr + pe;
      }
    }
  }
}

extern "C" void kernel_launch(void* const* d_in, const int* in_sizes, int n_in,
                              void* d_out, int out_size, void* d_ws, size_t ws_size,
                              hipStream_t stream) {
  const float* x   = (const float*)d_in[0];
  const float* Wqk = (const float*)d_in[1];
  const float* bqk = (const float*)d_in[2];
  const float* lw  = (const float*)d_in[3];
  const float* lb  = (const float*)d_in[4];
  float* out = (float*)d_out;

  char* ws = (char*)d_ws;
  u16* xb    = (u16*)(ws);                       // 33.55 MB  x bf16
  u16* qrb   = (u16*)(ws + 33554432ull);         // 33.55 MB  q_rope bf16
  u16* krb   = (u16*)(ws + 67108864ull);         // 33.55 MB  k_rope bf16
  u16* wb    = (u16*)(ws + 100663296ull);        //  4.19 MB  W bf16
  float* kmr = (float*)(ws + 104857600ull);      // 16 KB     fp32
  float* ctab= (float*)(ws + 104874368ull);      //  2 KB
  float* stab= (float*)(ws + 104876416ull);      //  2 KB
  u16* kvbT  = (u16*)(ws + 104878464ull);        // 0.5 MB    kv^T bf16
  float* zb  = (float*)(ws + 105402752ull);      //  1 MB     z fp32
  // kv partials (16.8 MB fp32) live in d_out scratch; attn overwrites all of out later.
  float* partial = out;

  hipMemsetAsync(kmr, 0, 16384ull, stream);      // atomic target only
  hipLaunchKernelGGL(trig_kernel, dim3(1), dim3(512), 0, stream, ctab, stab);
  hipLaunchKernelGGL(cast_kernel, dim3(2048), dim3(256), 0, stream, x, Wqk, xb, wb);
  hipLaunchKernelGGL(gemm_kernel, dim3(64, 8), dim3(512), 0, stream, xb, wb, bqk, ctab, stab, qrb, krb);
  hipLaunchKernelGGL(kvpart_kernel, dim3(1024), dim3(256), 0, stream, krb, xb, partial, kmr);
  hipLaunchKernelGGL(kvred_kernel, dim3(64), dim3(256), 0, stream, partial, kvbT);
  hipLaunchKernelGGL(z_kernel, dim3(1024), dim3(256), 0, stream, qrb, kmr, zb);
  hipLaunchKernelGGL(attn_kernel, dim3(32, 16, 4), dim3(256), 0, stream, qrb, kvbT, zb, x, lw, lb, out);
}

// Round 9
// 240.929 us; speedup vs baseline: 10.8411x; 1.0637x over previous
//
#include <hip/hip_runtime.h>
#include <hip/hip_bf16.h>
#include <math.h>

typedef unsigned short u16;
typedef __attribute__((ext_vector_type(8))) short s16x8;
typedef __attribute__((ext_vector_type(4))) float f32x4;

#define B_ 4
#define N_ 4096
#define C_ 1024
#define M_ (B_*N_)
#define NT_ 16   // K / 64

__device__ __forceinline__ u16 f2bf(float f) {
  unsigned u = __builtin_bit_cast(unsigned, f);
  u = u + 0x7fffu + ((u >> 16) & 1u);
  return (u16)(u >> 16);
}
__device__ __forceinline__ float bf2f(u16 h) {
  unsigned u = ((unsigned)h) << 16;
  return __builtin_bit_cast(float, u);
}

// ---------------- kernel T: one-time rope trig table (512 pairs) ----------------
__global__ void trig_kernel(float* __restrict__ ctab, float* __restrict__ stab) {
  const int i = threadIdx.x;   // 0..511
  const float theta = powf(10000.f, -(float)i * (1.f/512.f));
  ctab[i] = cosf(theta);
  stab[i] = sinf(theta);
}

// ---------------- kernel 0: fp32 -> bf16 precast of x and W ----------------
__global__ __launch_bounds__(256) void cast_kernel(
    const float* __restrict__ x, const float* __restrict__ w,
    u16* __restrict__ xb, u16* __restrict__ wb)
{
  const int NX4 = M_*C_/4;     // 4194304
  const int NW4 = 2048*C_/4;   // 524288
  int tid = blockIdx.x*256 + threadIdx.x;
  int stride = gridDim.x*256;
  for (int i = tid; i < NX4; i += stride) {
    f32x4 v = ((const f32x4*)x)[i];
    ushort4 o;
    o.x = f2bf(v[0]); o.y = f2bf(v[1]); o.z = f2bf(v[2]); o.w = f2bf(v[3]);
    ((ushort4*)xb)[i] = o;
  }
  for (int i = tid; i < NW4; i += stride) {
    f32x4 v = ((const f32x4*)w)[i];
    ushort4 o;
    o.x = f2bf(v[0]); o.y = f2bf(v[1]); o.z = f2bf(v[2]); o.w = f2bf(v[3]);
    ((ushort4*)wb)[i] = o;
  }
}

// ---------------- kernel 1: qk GEMM + bias + elu+1 + ROPE -> q_rope,k_rope ----
// 256x256 tile, BK=64, 8 waves (2M x 4N), dbuf LDS. Use-ordered split staging:
// B(kt+1)@p0, A-half-early@p1, A-half-late@p2; COUNTED waits vmcnt(6)@p1-end
// (drains A-late(kt)), vmcnt(2)@p3-end (drains B+A-early(kt+1)). Never drain-0
// mid-loop (T4). Ledger: steady-state 8 loads outstanding, dbuf-safe.
__global__ __launch_bounds__(512, 2) void gemm_kernel(
    const u16* __restrict__ xb, const u16* __restrict__ wb,
    const float* __restrict__ bqk,
    const float* __restrict__ ctab, const float* __restrict__ stab,
    u16* __restrict__ qrb, u16* __restrict__ krb)
{
  __shared__ __align__(16) unsigned char As[2][32768];  // [buf][256 rows][128B]
  __shared__ __align__(16) unsigned char Bs[2][32768];
  const int t = threadIdx.x;             // 0..511
  const int l = t & 63;
  const int w = t >> 6;                  // 0..7
  const int wm = w >> 2, wn = w & 3;     // 2M x 4N
  const int m0 = blockIdx.x * 256;
  const int n0 = blockIdx.y * 256;

  f32x4 acc[8][4];
  #pragma unroll
  for (int a = 0; a < 8; ++a)
    #pragma unroll
    for (int b = 0; b < 4; ++b) acc[a][b] = (f32x4){0.f,0.f,0.f,0.f};

  // staging: chunk jc = i*512 + t; row = i*64 + (t>>3); pre-swizzled source col
  const int s_cole = ((t & 7) ^ ((t >> 3) & 7)) << 3;      // element offset 0..56
  const size_t a_base = (size_t)(m0 + (t >> 3)) * 1024 + s_cole;
  const size_t b_base = (size_t)(n0 + (t >> 3)) * 1024 + s_cole;

  #define GLA(buf, kt, i_)                                                     \
    __builtin_amdgcn_global_load_lds(                                          \
      (const __attribute__((address_space(1))) void*)(xb + a_base + (size_t)(i_)*65536 + (kt)*64), \
      (__attribute__((address_space(3))) void*)(&As[buf][((i_)*512 + w*64)*16]), 16, 0, 0)
  #define GLB(buf, kt, i_)                                                     \
    __builtin_amdgcn_global_load_lds(                                          \
      (const __attribute__((address_space(1))) void*)(wb + b_base + (size_t)(i_)*65536 + (kt)*64), \
      (__attribute__((address_space(3))) void*)(&Bs[buf][((i_)*512 + w*64)*16]), 16, 0, 0)

  // prologue: stage kt=0 fully, full drain
  GLA(0,0,0); GLA(0,0,1); GLA(0,0,2); GLA(0,0,3);
  GLB(0,0,0); GLB(0,0,1); GLB(0,0,2); GLB(0,0,3);
  asm volatile("s_waitcnt vmcnt(0)" ::: "memory");
  __builtin_amdgcn_s_barrier();

  for (int kt = 0; kt < NT_; ++kt) {
    const int cur = kt & 1;
    const int nx = cur ^ 1;
    const unsigned char* Ab = As[cur];
    const unsigned char* Bb = Bs[cur];
    s16x8 bfr[4][2];
    #pragma unroll
    for (int p = 0; p < 4; ++p) {
      // this phase's A fragments (quadrant p: mf 2p, 2p+1)
      s16x8 af[2][2];
      #pragma unroll
      for (int f = 0; f < 2; ++f) {
        const int r = wm*128 + (2*p + f)*16 + (l & 15);
        #pragma unroll
        for (int ks = 0; ks < 2; ++ks) {
          const int kbyte = ks*64 + ((l >> 4) << 4);
          af[f][ks] = *(const s16x8*)(Ab + r*128 + (kbyte ^ ((r & 7) << 4)));
        }
      }
      if (p == 0) {   // B fragments for whole kt
        #pragma unroll
        for (int nf = 0; nf < 4; ++nf) {
          const int r = wn*64 + nf*16 + (l & 15);
          #pragma unroll
          for (int ks = 0; ks < 2; ++ks) {
            const int kbyte = ks*64 + ((l >> 4) << 4);
            bfr[nf][ks] = *(const s16x8*)(Bb + r*128 + (kbyte ^ ((r & 7) << 4)));
          }
        }
      }
      // use-ordered staging of kt+1 into buf nx
      if (kt + 1 < NT_) {
        if (p == 0) { GLB(nx, kt+1, 0); GLB(nx, kt+1, 1); GLB(nx, kt+1, 2); GLB(nx, kt+1, 3); }
        if (p == 1) { GLA(nx, kt+1, 0); GLA(nx, kt+1, 2); }   // rows 0-63, 128-191 (q0/q1)
        if (p == 2) { GLA(nx, kt+1, 1); GLA(nx, kt+1, 3); }   // rows 64-127, 192-255 (q2/q3)
      }
      __builtin_amdgcn_s_barrier();
      __builtin_amdgcn_s_setprio(1);
      #pragma unroll
      for (int f = 0; f < 2; ++f)
        #pragma unroll
        for (int nf = 0; nf < 4; ++nf)
          #pragma unroll
          for (int ks = 0; ks < 2; ++ks)
            acc[2*p + f][nf] = __builtin_amdgcn_mfma_f32_16x16x32_bf16(
                af[f][ks], bfr[nf][ks], acc[2*p + f][nf], 0, 0, 0);
      __builtin_amdgcn_s_setprio(0);
      if (p == 1) {
        // drain A-late(kt) (staged at kt-1 p2, 3-phase cover); keep kt+1 stage in flight
        if (kt < NT_ - 1) asm volatile("s_waitcnt vmcnt(6)" ::: "memory");
        else              asm volatile("s_waitcnt vmcnt(0)" ::: "memory");
      }
      if (p == 3 && kt + 1 < NT_) {
        // drain B(kt+1)+A-early(kt+1) (2-3 phase cover); keep A-late(kt+1) in flight
        asm volatile("s_waitcnt vmcnt(2)" ::: "memory");
      }
      __builtin_amdgcn_s_barrier();
    }
  }
  #undef GLA
  #undef GLB

  // epilogue: bias + elu+1, rope via shfl_xor(1), split q/k (block-uniform)
  #pragma unroll
  for (int nf = 0; nf < 4; ++nf) {
    const int col = n0 + wn*64 + nf*16 + (l & 15);   // 0..2047
    const float bias = bqk[col];
    const int cc = col & 1023;
    const float cn = ctab[cc >> 1];
    const float sn = stab[cc >> 1];
    u16* dst = (col < 1024) ? qrb : krb;
    #pragma unroll
    for (int mf = 0; mf < 8; ++mf) {
      #pragma unroll
      for (int j = 0; j < 4; ++j) {
        const int rowm = m0 + wm*128 + mf*16 + ((l >> 4) << 2) + j;
        float v = acc[mf][nf][j] + bias;
        v = (v > 0.f) ? (v + 1.f) : __expf(v);      // elu(v)+1
        const float vp = __shfl_xor(v, 1);          // partner column (elu'd)
        const float vr = (col & 1) ? (sn*vp + cn*v) : (cn*v - sn*vp);
        dst[(size_t)rowm*1024 + cc] = f2bf(vr);
      }
    }
  }
}

// ---------------- kernel 2: kv partials: 8d x 8e per thread, 16 n-slices ----------
__global__ __launch_bounds__(256, 4) void kvpart_kernel(
    const u16* __restrict__ krb, const u16* __restrict__ xb,
    float* __restrict__ partial, float* __restrict__ kmr)
{
  __shared__ float red[2][64][65];   // odd stride: conflict-free lane columns
  const int t = threadIdx.x;
  const int l = t & 63;
  const int nsub = t >> 6;
  const int dg = l >> 3, eg = l & 7;
  const int d0 = dg*8, e0 = eg*8;
  const int blk = blockIdx.x;
  const int bh = blk >> 4;
  const int ns = blk & 15;
  const int b = bh >> 4, h = bh & 15;

  float acc[8][8];
  #pragma unroll
  for (int i=0;i<8;++i)
    #pragma unroll
    for (int j=0;j<8;++j) acc[i][j]=0.f;
  float ksum[8];
  #pragma unroll
  for (int i=0;i<8;++i) ksum[i]=0.f;

  const size_t base = ((size_t)b*4096 + ns*256 + nsub*64) * 1024 + h*64;
  #pragma unroll 2
  for (int it = 0; it < 64; ++it) {
    const size_t roff = base + (size_t)it*1024;
    const s16x8 k8 = *(const s16x8*)(krb + roff + d0);
    const s16x8 v8 = *(const s16x8*)(xb + roff + e0);
    float kf[8], vf[8];
    #pragma unroll
    for (int i=0;i<8;++i){ kf[i]=bf2f((u16)k8[i]); vf[i]=bf2f((u16)v8[i]); }
    #pragma unroll
    for (int i=0;i<8;++i){
      ksum[i]+=kf[i];
      #pragma unroll
      for (int j=0;j<8;++j) acc[i][j] += kf[i]*vf[j];
    }
  }

  if (nsub >= 2) {
    #pragma unroll
    for (int i=0;i<8;++i)
      #pragma unroll
      for (int j=0;j<8;++j) red[nsub-2][l][i*8+j] = acc[i][j];
  }
  __syncthreads();
  if (nsub < 2) {
    #pragma unroll
    for (int i=0;i<8;++i)
      #pragma unroll
      for (int j=0;j<8;++j) acc[i][j] += red[nsub][l][i*8+j];
  }
  __syncthreads();
  if (nsub == 1) {
    #pragma unroll
    for (int i=0;i<8;++i)
      #pragma unroll
      for (int j=0;j<8;++j) red[0][l][i*8+j] = acc[i][j];
  }
  __syncthreads();
  if (nsub == 0) {
    float* dst = partial + ((size_t)ns*64 + bh)*4096 + d0*64 + e0;
    #pragma unroll
    for (int i=0;i<8;++i) {
      f32x4 lo, hi;
      #pragma unroll
      for (int j=0;j<4;++j) { lo[j] = acc[i][j] + red[0][l][i*8+j];
                              hi[j] = acc[i][j+4] + red[0][l][i*8+j+4]; }
      *(f32x4*)(dst + i*64)     = lo;
      *(f32x4*)(dst + i*64 + 4) = hi;
    }
  }
  if (eg == 0) {
    #pragma unroll
    for (int i=0;i<8;++i)
      atomicAdd(kmr + bh*64 + d0 + i, ksum[i] * (1.f/4096.f));
  }
}

// ---------------- kernel 2b: sum 16 partial slices, *1/n, transpose -> kvbT bf16 ----
__global__ __launch_bounds__(256) void kvred_kernel(
    const float* __restrict__ partial, u16* __restrict__ kvbT)
{
  __shared__ float s[4096];
  const int bh = blockIdx.x;
  const int t = threadIdx.x;
  f32x4 a0={0,0,0,0}, a1={0,0,0,0}, a2={0,0,0,0}, a3={0,0,0,0};
  #pragma unroll
  for (int sl=0; sl<16; ++sl) {
    const f32x4* p = (const f32x4*)(partial + ((size_t)sl*64 + bh)*4096 + t*16);
    a0 += p[0]; a1 += p[1]; a2 += p[2]; a3 += p[3];
  }
  ((f32x4*)s)[t*4+0]=a0; ((f32x4*)s)[t*4+1]=a1;
  ((f32x4*)s)[t*4+2]=a2; ((f32x4*)s)[t*4+3]=a3;
  __syncthreads();
  const float inv_n = 1.f / 4096.f;
  s16x8 o0, o1;
  #pragma unroll
  for (int j=0;j<8;++j) {
    o0[j] = (short)f2bf(s[((t&3)*16 + j)*64 + (t>>2)] * inv_n);
    o1[j] = (short)f2bf(s[((t&3)*16 + 8 + j)*64 + (t>>2)] * inv_n);
  }
  *(s16x8*)(kvbT + (size_t)bh*4096 + t*16) = o0;
  *(s16x8*)(kvbT + (size_t)bh*4096 + t*16 + 8) = o1;
}

// ---------------- kernel 3: attn MFMA + fused z + z scale + fused pe conv ----------
// per (b,h): [4096x64] @ [64x64]. BM=128 rows/block, 4 waves, K=64.
// z computed in-kernel from staged q (As) and kmr -> zs[128] (z_kernel removed).
__global__ __launch_bounds__(256) void attn_kernel(
    const u16* __restrict__ qrb, const u16* __restrict__ kvbT,
    const float* __restrict__ kmr, const float* __restrict__ x,
    const float* __restrict__ lw, const float* __restrict__ lb,
    float* __restrict__ out)
{
  __shared__ __align__(16) unsigned char As[16384]; // 128 rows x 128B
  __shared__ __align__(16) unsigned char Bs[8192];  // 64 rows x 128B
  __shared__ float lws[192], lbs[64];
  __shared__ float kms[64];
  __shared__ float zs[128];
  const int t = threadIdx.x, l = t & 63, w = t >> 6;
  const int m0 = blockIdx.x * 128;
  const int h = blockIdx.y, b = blockIdx.z;
  const size_t qbase = ((size_t)b*4096 + m0) * 1024 + h*64;
  const u16* kvsrc = kvbT + ((size_t)(b*16 + h) << 12);

  #pragma unroll
  for (int i = 0; i < 4; ++i) {
    const int jc   = i*256 + t;
    const int row  = jc >> 3;                          // 0..127
    const int cole = (((jc & 7) << 4) ^ ((row & 7) << 4)) >> 1;
    const int ldsoff = (i*256 + w*64) * 16;
    __builtin_amdgcn_global_load_lds(
      (const __attribute__((address_space(1))) void*)(qrb + qbase + (size_t)row*1024 + cole),
      (__attribute__((address_space(3))) void*)(As + ldsoff), 16, 0, 0);
  }
  #pragma unroll
  for (int i = 0; i < 2; ++i) {
    const int jc   = i*256 + t;
    const int row  = jc >> 3;                          // e: 0..63
    const int cole = (((jc & 7) << 4) ^ ((row & 7) << 4)) >> 1;
    const int ldsoff = (i*256 + w*64) * 16;
    __builtin_amdgcn_global_load_lds(
      (const __attribute__((address_space(1))) void*)(kvsrc + (size_t)row*64 + cole),
      (__attribute__((address_space(3))) void*)(Bs + ldsoff), 16, 0, 0);
  }
  if (t < 192) lws[t] = lw[h*192 + t];
  if (t >= 192)  lbs[t-192] = lb[h*64 + (t-192)];
  if (t < 64) kms[t] = kmr[(b*16 + h)*64 + t];
  __syncthreads();

  // fused z: row r = t>>1, d-half = t&1; q from swizzled As
  {
    const int r = t >> 1, half = t & 1;
    const int swz = (r & 7) << 4;
    float zp = 0.f;
    #pragma unroll
    for (int c = 0; c < 4; ++c) {
      const int kb = half*64 + c*16;
      const s16x8 qv = *(const s16x8*)(As + r*128 + (kb ^ swz));
      #pragma unroll
      for (int j = 0; j < 8; ++j) zp += bf2f((u16)qv[j]) * kms[half*32 + c*8 + j];
    }
    zp += __shfl_xor(zp, 1);
    if (!half) zs[r] = 1.f / (zp + 1e-6f);
  }

  f32x4 acc[2][4];
  #pragma unroll
  for (int a = 0; a < 2; ++a)
    #pragma unroll
    for (int c = 0; c < 4; ++c) acc[a][c] = (f32x4){0.f,0.f,0.f,0.f};

  #pragma unroll
  for (int ks = 0; ks < 2; ++ks) {
    const int kbyte = ks*64 + ((l >> 4) << 4);
    s16x8 af[2], bf[4];
    #pragma unroll
    for (int mi = 0; mi < 2; ++mi) {
      const int r = w*32 + mi*16 + (l & 15);
      af[mi] = *(const s16x8*)(As + r*128 + (kbyte ^ ((r & 7) << 4)));
    }
    #pragma unroll
    for (int ni = 0; ni < 4; ++ni) {
      const int r = ni*16 + (l & 15);
      bf[ni] = *(const s16x8*)(Bs + r*128 + (kbyte ^ ((r & 7) << 4)));
    }
    #pragma unroll
    for (int mi = 0; mi < 2; ++mi)
      #pragma unroll
      for (int ni = 0; ni < 4; ++ni)
        acc[mi][ni] = __builtin_amdgcn_mfma_f32_16x16x32_bf16(af[mi], bf[ni], acc[mi][ni], 0, 0, 0);
  }
  __syncthreads();   // zs ready for epilogue

  // epilogue: out = acc * z[row] + pe(x)
  #pragma unroll
  for (int mi = 0; mi < 2; ++mi) {
    #pragma unroll
    for (int j = 0; j < 4; ++j) {
      const int rowm = m0 + w*32 + mi*16 + ((l >> 4) << 2) + j;
      const float zr = zs[rowm - m0];
      const size_t rbase = ((size_t)b*4096 + rowm)*1024;
      #pragma unroll
      for (int ni = 0; ni < 4; ++ni) {
        const int cl = ni*16 + (l & 15);       // in-head channel 0..63
        const int c = h*64 + cl;
        float pe = lbs[cl] + x[rbase + c]*lws[cl*3+1];
        if (rowm > 0)    pe += x[rbase - 1024 + c]*lws[cl*3];
        if (rowm < 4095) pe += x[rbase + 1024 + c]*lws[cl*3+2];
        out[rbase + c] = acc[mi][ni][j]*zr + pe;
      }
    }
  }
}

extern "C" void kernel_launch(void* const* d_in, const int* in_sizes, int n_in,
                              void* d_out, int out_size, void* d_ws, size_t ws_size,
                              hipStream_t stream) {
  const float* x   = (const float*)d_in[0];
  const float* Wqk = (const float*)d_in[1];
  const float* bqk = (const float*)d_in[2];
  const float* lw  = (const float*)d_in[3];
  const float* lb  = (const float*)d_in[4];
  float* out = (float*)d_out;

  char* ws = (char*)d_ws;
  u16* xb    = (u16*)(ws);                       // 33.55 MB  x bf16
  u16* qrb   = (u16*)(ws + 33554432ull);         // 33.55 MB  q_rope bf16
  u16* krb   = (u16*)(ws + 67108864ull);         // 33.55 MB  k_rope bf16
  u16* wb    = (u16*)(ws + 100663296ull);        //  4.19 MB  W bf16
  float* kmr = (float*)(ws + 104857600ull);      // 16 KB     fp32
  float* ctab= (float*)(ws + 104874368ull);      //  2 KB
  float* stab= (float*)(ws + 104876416ull);      //  2 KB
  u16* kvbT  = (u16*)(ws + 104878464ull);        // 0.5 MB    kv^T bf16
  // kv partials (16.8 MB fp32) live in d_out scratch; attn overwrites all of out later.
  float* partial = out;

  hipMemsetAsync(kmr, 0, 16384ull, stream);      // atomic target only
  hipLaunchKernelGGL(trig_kernel, dim3(1), dim3(512), 0, stream, ctab, stab);
  hipLaunchKernelGGL(cast_kernel, dim3(2048), dim3(256), 0, stream, x, Wqk, xb, wb);
  hipLaunchKernelGGL(gemm_kernel, dim3(64, 8), dim3(512), 0, stream, xb, wb, bqk, ctab, stab, qrb, krb);
  hipLaunchKernelGGL(kvpart_kernel, dim3(1024), dim3(256), 0, stream, krb, xb, partial, kmr);
  hipLaunchKernelGGL(kvred_kernel, dim3(64), dim3(256), 0, stream, partial, kvbT);
  hipLaunchKernelGGL(attn_kernel, dim3(32, 16, 4), dim3(256), 0, stream, qrb, kvbT, kmr, x, lw, lb, out);
}